// Round 1
// 183.704 us; speedup vs baseline: 1.0184x; 1.0184x over previous
//
#include <hip/hip_runtime.h>

typedef unsigned int uint32;

__device__ __forceinline__ float fexp2(float x) { return __builtin_amdgcn_exp2f(x); }
__device__ __forceinline__ float flog2(float x) { return __builtin_amdgcn_logf(x); }

__device__ __forceinline__ float s2lin(float c) {
    float p = fexp2(flog2((c + 0.055f) * (1.0f / 1.055f)) * 2.4f);
    return c > 0.04045f ? p : c * (1.0f / 12.92f);
}

__device__ __forceinline__ float labf(float t) {
    float p = fexp2(flog2(t) * (1.0f / 3.0f));
    return t > 0.008856f ? p : 7.787f * t + (16.0f / 116.0f);
}

__device__ __forceinline__ void px(float r, float g, float b,
                                   float& L, float& a01, float& b01) {
    float lr = s2lin(r), lg = s2lin(g), lb = s2lin(b);
    // RGB2XYZ rows pre-divided by D65 white (0.95047, 1.0, 1.08883)
    float X = 0.43395300f * lr + 0.37621900f * lg + 0.18982460f * lb;
    float Y = 0.21267100f * lr + 0.71516000f * lg + 0.07216900f * lb;
    float Z = 0.01775660f * lr + 0.10946970f * lg + 0.87270740f * lb;
    float fx = labf(X), fy = labf(Y), fz = labf(Z);
    L   = 116.0f * fy - 16.0f;                              // L in [0,100]
    a01 = (500.0f * (fx - fy) + 128.0f) * (1.0f / 255.0f);  // in (0,1) for this matrix
    b01 = (200.0f * (fy - fz) + 128.0f) * (1.0f / 255.0f);  // in (0,1)
}

// Fully fused: one block per image (16384 px), 1024 threads x 16 px each.
// Per-thread Lab state lives in 16 VGPRs packed as u8 a | u8 b<<8 | f16 L<<16
// (identical quantization to the verified two-pass kernel -> bit-identical output).
// No workspace, no intermediate HBM round-trip, single launch.
__global__ __launch_bounds__(1024) void k_fused(const float* __restrict__ x,
                                                float* __restrict__ out) {
    const int img = blockIdx.x, t = threadIdx.x;
    const size_t base = (size_t)img * 49152;   // 16384 px * 3 floats
    const float* __restrict__ in = x + base;
    float* __restrict__ o = out + base;

    uint32 pk[16];
    float m1 = 3.4e38f, m2 = 3.4e38f;          // min(L), min(100-L)
#pragma unroll
    for (int i = 0; i < 16; ++i) {
        const int p = t + (i << 10);           // pixel index, unit stride across lanes
        const float* q = in + 3 * p;           // 12 B/lane, coalesced dwordx3
        float L, a01, b01;
        px(q[0], q[1], q[2], L, a01, b01);
        m1 = fminf(m1, L);
        m2 = fminf(m2, 100.0f - L);
        uint32 au = (uint32)(a01 * 255.0f + 0.5f);
        uint32 bu = (uint32)(b01 * 255.0f + 0.5f);
        unsigned short hb = __builtin_bit_cast(unsigned short, (_Float16)L);
        pk[i] = au | (bu << 8) | ((uint32)hb << 16);
    }

    // wave reduce (64 lanes), then block reduce via tiny LDS
#pragma unroll
    for (int m = 32; m; m >>= 1) {
        m1 = fminf(m1, __shfl_xor(m1, m, 64));
        m2 = fminf(m2, __shfl_xor(m2, m, 64));
    }
    __shared__ float sm[32];                   // 16 waves x {minL, min(100-L)}
    if ((t & 63) == 0) { sm[(t >> 6) * 2] = m1; sm[(t >> 6) * 2 + 1] = m2; }
    __syncthreads();
    float Lmin = 3.4e38f, M2 = 3.4e38f;
#pragma unroll
    for (int i = 0; i < 16; ++i) {             // broadcast LDS reads, conflict-free
        Lmin = fminf(Lmin, sm[2 * i]);
        M2   = fminf(M2,   sm[2 * i + 1]);
    }
    const float s = 1.0f / ((100.0f - M2) - Lmin);

#pragma unroll
    for (int i = 0; i < 16; ++i) {
        const int p = t + (i << 10);
        const uint32 v = pk[i];
        float a01 = (float)(v & 255u) * (1.0f / 255.0f);
        float b01 = (float)((v >> 8) & 255u) * (1.0f / 255.0f);
        float L = (float)__builtin_bit_cast(_Float16, (unsigned short)(v >> 16));
        float* q = o + 3 * p;                  // 12 B/lane, coalesced dwordx3
        q[0] = (L - Lmin) * s;
        q[1] = a01;
        q[2] = b01;
    }
}

extern "C" void kernel_launch(void* const* d_in, const int* in_sizes, int n_in,
                              void* d_out, int out_size, void* d_ws, size_t ws_size,
                              hipStream_t stream) {
    (void)in_sizes; (void)n_in; (void)out_size; (void)d_ws; (void)ws_size;
    const float* x = (const float*)d_in[0];
    float* out = (float*)d_out;
    k_fused<<<512, 1024, 0, stream>>>(x, out);
}